// Round 9
// baseline (453.932 us; speedup 1.0000x reference)
//
#include <hip/hip_runtime.h>
#include <cmath>

// Problem geometry (fixed by the reference): 128 images of 512x512 f32.
static constexpr int IMH = 512;
static constexpr int IMW = 512;
static constexpr int IMG_PIX = IMH * IMW;

struct Weights {
    float kx[7];
    float ky[13];
};

__global__ void init_minmax_kernel(int* __restrict__ mm, int nimg) {
    int i = blockIdx.x * blockDim.x + threadIdx.x;
    if (i < nimg) {
        mm[2 * i]     = 0x7f7fffff;  // +FLT_MAX bits (min accumulator)
        mm[2 * i + 1] = 0;           // 0.0f bits (max accumulator; blur > 0)
    }
}

__device__ __forceinline__ float gm_bperm(int addr, float v) {
    return __int_as_float(__builtin_amdgcn_ds_bpermute(addr, __float_as_int(v)));
}

// Pair-column column-sweep fused kernel: zero LDS-array, zero barriers.
// Each lane owns TWO adjacent columns (a=even, b=a+1) -> 120 output cols per
// wave (lanes 2..61), 2-lane halo each side. Reflection preserves parity, so
// per-tap bpermute source addresses (reflect folded in) stay register-stable.
// 8 bpermutes serve 2 columns; float2 loads/stores; 13-reg ring per column.
// Grid 5x2x128 * 4 waves = 5120 waves -> single residency round, no tail.
__global__ __launch_bounds__(256, 8) void blur_kernel(
        const float* __restrict__ in, float* __restrict__ blur,
        int* __restrict__ mm, Weights wt) {
#pragma clang fp contract(off)
    const int band = blockIdx.x;                 // 0..4
    const int img  = blockIdx.z;                 // 0..127
    const int kk   = blockIdx.y * 4 + (threadIdx.x >> 6);  // chunk 0..7
    const int lane = threadIdx.x & 63;
    const int P0   = band * 120 - 4;             // wave covers cols P0..P0+127
    const int a    = P0 + 2 * lane;              // lo col (even)
    const int a_ld = min(max(a, 0), IMW - 2);    // clamped float2 load col
    const bool cvalid = (lane >= 2) && (lane <= 61) && (a <= IMW - 1);
    const bool zl = (a == 0);                    // lo col at left image edge
    const bool zr = (a == IMW - 2);              // hi col at right image edge

    const float* __restrict__ ip = in + (size_t)img * IMG_PIX;
    float* __restrict__ bp = blur + (size_t)img * IMG_PIX;

    // Per-tap bpermute byte addresses (blurX reflect folded; parity-stable).
    int A_m3hi, A_m1hi, A_p3hi, A_m2lo, A_p2lo, A_p4lo;
    {
        int t, r;
        t = a - 3; r = t < 0 ? -t : (t > IMW - 1 ? 2 * (IMW - 1) - t : t); A_m3hi = (((r - P0) >> 1) & 63) << 2;
        t = a - 1; r = t < 0 ? -t : (t > IMW - 1 ? 2 * (IMW - 1) - t : t); A_m1hi = (((r - P0) >> 1) & 63) << 2;
        t = a + 3; r = t < 0 ? -t : (t > IMW - 1 ? 2 * (IMW - 1) - t : t); A_p3hi = (((r - P0) >> 1) & 63) << 2;
        t = a - 2; r = t < 0 ? -t : (t > IMW - 1 ? 2 * (IMW - 1) - t : t); A_m2lo = (((r - P0) >> 1) & 63) << 2;
        t = a + 2; r = t < 0 ? -t : (t > IMW - 1 ? 2 * (IMW - 1) - t : t); A_p2lo = (((r - P0) >> 1) & 63) << 2;
        t = a + 4; r = t < 0 ? -t : (t > IMW - 1 ? 2 * (IMW - 1) - t : t); A_p4lo = (((r - P0) >> 1) & 63) << 2;
    }

    // Chunk kk: output rows 64kk..64kk+63; sweep rows gr0..gr0+R-1.
    const int gr0    = (kk == 0) ? 0 : 64 * kk - 6;
    const int tail_n = (kk == 0 || kk == 7) ? 5 : 11;   // R-65, R=70 or 76

    const float2* xp2 = reinterpret_cast<const float2*>(ip) + (size_t)gr0 * (IMW / 2) + (a_ld >> 1);
    float2 zero2 = make_float2(0.0f, 0.0f);
    float2 x_prev = (kk == 0) ? zero2 : xp2[-(IMW / 2)];
    float2 x_cur  = xp2[0];
    float2 x_next = xp2[IMW / 2];
    const float2* xpref2 = xp2 + 2 * (IMW / 2);
    float2* op2 = reinterpret_cast<float2*>(bp + (size_t)(gr0 + 6) * IMW + a_ld);

    float wl[13], wh[13];                         // per-col bx rings, static idx
    float tmn = 3.402823466e38f;
    float tmx = 0.0f;

#define GM_ROW(S, DO_OUT, ISLAST, PREF)                                        \
    {                                                                          \
        float2 x_pref = (PREF);                                                \
        float xm1h = gm_bperm(A_m1hi, x_cur.y);   /* x[a-1] */                 \
        float xp2l = gm_bperm(A_p2lo, x_cur.x);   /* x[a+2] */                 \
        float lf_lo = zl ? 0.0f : xm1h;                                        \
        float rt_hi = zr ? 0.0f : xp2l;                                        \
        float dn_lo = (ISLAST) ? 0.0f : x_next.x;                              \
        float dn_hi = (ISLAST) ? 0.0f : x_next.y;                              \
        float gv_lo = dn_lo - x_prev.x;                                        \
        float gh_lo = x_cur.y - lf_lo;                                         \
        float sg_lo = gv_lo * gv_lo + gh_lo * gh_lo;                           \
        sg_lo = sg_lo + 1e-6f;                                                 \
        float g_lo = sqrtf(sg_lo);                                             \
        float gv_hi = dn_hi - x_prev.y;                                        \
        float gh_hi = rt_hi - x_cur.x;                                         \
        float sg_hi = gv_hi * gv_hi + gh_hi * gh_hi;                           \
        sg_hi = sg_hi + 1e-6f;                                                 \
        float g_hi = sqrtf(sg_hi);                                             \
        float gm3h = gm_bperm(A_m3hi, g_hi);                                   \
        float gm2l = gm_bperm(A_m2lo, g_lo);                                   \
        float gm1h = gm_bperm(A_m1hi, g_hi);                                   \
        float gp2l = gm_bperm(A_p2lo, g_lo);                                   \
        float gp3h = gm_bperm(A_p3hi, g_hi);                                   \
        float gp4l = gm_bperm(A_p4lo, g_lo);                                   \
        float ax_lo = 0.0f;                                                    \
        ax_lo += wt.kx[0] * gm3h;                                              \
        ax_lo += wt.kx[1] * gm2l;                                              \
        ax_lo += wt.kx[2] * gm1h;                                              \
        ax_lo += wt.kx[3] * g_lo;                                              \
        ax_lo += wt.kx[4] * g_hi;                                              \
        ax_lo += wt.kx[5] * gp2l;                                              \
        ax_lo += wt.kx[6] * gp3h;                                              \
        float ax_hi = 0.0f;                                                    \
        ax_hi += wt.kx[0] * gm2l;                                              \
        ax_hi += wt.kx[1] * gm1h;                                              \
        ax_hi += wt.kx[2] * g_lo;                                              \
        ax_hi += wt.kx[3] * g_hi;                                              \
        ax_hi += wt.kx[4] * gp2l;                                              \
        ax_hi += wt.kx[5] * gp3h;                                              \
        ax_hi += wt.kx[6] * gp4l;                                              \
        wl[(S) % 13] = ax_lo;                                                  \
        wh[(S) % 13] = ax_hi;                                                  \
        if (DO_OUT) {                                                          \
            float ay_lo = 0.0f, ay_hi = 0.0f;                                  \
            ay_lo += wt.ky[0]  * wl[((S) + 1)  % 13];                          \
            ay_lo += wt.ky[1]  * wl[((S) + 2)  % 13];                          \
            ay_lo += wt.ky[2]  * wl[((S) + 3)  % 13];                          \
            ay_lo += wt.ky[3]  * wl[((S) + 4)  % 13];                          \
            ay_lo += wt.ky[4]  * wl[((S) + 5)  % 13];                          \
            ay_lo += wt.ky[5]  * wl[((S) + 6)  % 13];                          \
            ay_lo += wt.ky[6]  * wl[((S) + 7)  % 13];                          \
            ay_lo += wt.ky[7]  * wl[((S) + 8)  % 13];                          \
            ay_lo += wt.ky[8]  * wl[((S) + 9)  % 13];                          \
            ay_lo += wt.ky[9]  * wl[((S) + 10) % 13];                          \
            ay_lo += wt.ky[10] * wl[((S) + 11) % 13];                          \
            ay_lo += wt.ky[11] * wl[((S) + 12) % 13];                          \
            ay_lo += wt.ky[12] * wl[((S) + 13) % 13];                          \
            ay_hi += wt.ky[0]  * wh[((S) + 1)  % 13];                          \
            ay_hi += wt.ky[1]  * wh[((S) + 2)  % 13];                          \
            ay_hi += wt.ky[2]  * wh[((S) + 3)  % 13];                          \
            ay_hi += wt.ky[3]  * wh[((S) + 4)  % 13];                          \
            ay_hi += wt.ky[4]  * wh[((S) + 5)  % 13];                          \
            ay_hi += wt.ky[5]  * wh[((S) + 6)  % 13];                          \
            ay_hi += wt.ky[6]  * wh[((S) + 7)  % 13];                          \
            ay_hi += wt.ky[7]  * wh[((S) + 8)  % 13];                          \
            ay_hi += wt.ky[8]  * wh[((S) + 9)  % 13];                          \
            ay_hi += wt.ky[9]  * wh[((S) + 10) % 13];                          \
            ay_hi += wt.ky[10] * wh[((S) + 11) % 13];                          \
            ay_hi += wt.ky[11] * wh[((S) + 12) % 13];                          \
            ay_hi += wt.ky[12] * wh[((S) + 13) % 13];                          \
            if (cvalid) {                                                      \
                *op2 = make_float2(ay_lo, ay_hi);                              \
                tmn = fminf(tmn, ay_lo);                                       \
                tmx = fmaxf(tmx, ay_lo);                                       \
                tmn = fminf(tmn, ay_hi);                                       \
                tmx = fmaxf(tmx, ay_hi);                                       \
            }                                                                  \
            op2 += IMW / 2;                                                    \
        }                                                                      \
        x_prev = x_cur; x_cur = x_next; x_next = x_pref;                       \
        xpref2 += IMW / 2;                                                     \
    }

    // ---- peel: ring fill, rows gr0..gr0+12 (one output at s=12) ----
    GM_ROW(0,  false, false, xpref2[0])
    GM_ROW(1,  false, false, xpref2[0])
    GM_ROW(2,  false, false, xpref2[0])
    GM_ROW(3,  false, false, xpref2[0])
    GM_ROW(4,  false, false, xpref2[0])
    GM_ROW(5,  false, false, xpref2[0])
    GM_ROW(6,  false, false, xpref2[0])
    GM_ROW(7,  false, false, xpref2[0])
    GM_ROW(8,  false, false, xpref2[0])
    GM_ROW(9,  false, false, xpref2[0])
    GM_ROW(10, false, false, xpref2[0])
    GM_ROW(11, false, false, xpref2[0])
    GM_ROW(12, true,  false, xpref2[0])

    // ---- top reflected outputs (kk==0: rows 0..5 from ring rows 0..11) ----
    if (kk == 0) {
        #pragma unroll
        for (int orow = 0; orow < 6; ++orow) {
            float ay_lo = 0.0f, ay_hi = 0.0f;
            #pragma unroll
            for (int j = 0; j < 13; ++j) {
                int t = orow + j - 6;
                t = t < 0 ? -t : t;              // compile-time per (orow,j)
                ay_lo += wt.ky[j] * wl[t];       // slot == row for kk==0
                ay_hi += wt.ky[j] * wh[t];
            }
            if (cvalid) {
                *reinterpret_cast<float2*>(bp + (size_t)orow * IMW + a_ld) =
                    make_float2(ay_lo, ay_hi);
                tmn = fminf(tmn, ay_lo); tmx = fmaxf(tmx, ay_lo);
                tmn = fminf(tmn, ay_hi); tmx = fmaxf(tmx, ay_hi);
            }
        }
    }

    // ---- main loop: rows gr0+13 .. gr0+64, fully guard-free ----
    for (int giter = 1; giter <= 4; ++giter) {
        GM_ROW(0,  true, false, xpref2[0])
        GM_ROW(1,  true, false, xpref2[0])
        GM_ROW(2,  true, false, xpref2[0])
        GM_ROW(3,  true, false, xpref2[0])
        GM_ROW(4,  true, false, xpref2[0])
        GM_ROW(5,  true, false, xpref2[0])
        GM_ROW(6,  true, false, xpref2[0])
        GM_ROW(7,  true, false, xpref2[0])
        GM_ROW(8,  true, false, xpref2[0])
        GM_ROW(9,  true, false, xpref2[0])
        GM_ROW(10, true, false, xpref2[0])
        GM_ROW(11, true, false, xpref2[0])
        GM_ROW(12, true, false, xpref2[0])
    }

    // ---- tail: rows gr0+65 .. gr0+R-1 (5 or 11 rows), guarded ----
    // slot (65+S)%13 == S; row 511 (kk==7, S==4) takes dn=0; prefetch guarded.
#define GM_TAILROW(S)                                                          \
    if ((S) < tail_n) {                                                        \
        GM_ROW(S, true,                                                        \
               ((gr0 + 65 + (S)) == IMH - 1),                                  \
               ((gr0 + 67 + (S)) <= IMH - 1) ? xpref2[0] : zero2)              \
    }
    GM_TAILROW(0)
    GM_TAILROW(1)
    GM_TAILROW(2)
    GM_TAILROW(3)
    GM_TAILROW(4)
    GM_TAILROW(5)
    GM_TAILROW(6)
    GM_TAILROW(7)
    GM_TAILROW(8)
    GM_TAILROW(9)
    GM_TAILROW(10)
#undef GM_TAILROW
#undef GM_ROW

    // ---- bottom reflected outputs (kk==7: rows 506..511) ----
    // Row t (500..511) sits at slot (t-442)%13 after the 70-row sweep.
    if (kk == 7) {
        #pragma unroll
        for (int oo = 0; oo < 6; ++oo) {
            int orow = 506 + oo;
            float ay_lo = 0.0f, ay_hi = 0.0f;
            #pragma unroll
            for (int j = 0; j < 13; ++j) {
                int t = orow + j - 6;
                t = t > IMH - 1 ? 2 * (IMH - 1) - t : t;  // compile-time
                ay_lo += wt.ky[j] * wl[(t - 442) % 13];
                ay_hi += wt.ky[j] * wh[(t - 442) % 13];
            }
            if (cvalid) {
                *reinterpret_cast<float2*>(bp + (size_t)orow * IMW + a_ld) =
                    make_float2(ay_lo, ay_hi);
                tmn = fminf(tmn, ay_lo); tmx = fmaxf(tmx, ay_lo);
                tmn = fminf(tmn, ay_hi); tmx = fmaxf(tmx, ay_hi);
            }
        }
    }

    // ---- per-wave reduce + per-image atomics ----
    #pragma unroll
    for (int off = 32; off > 0; off >>= 1) {
        tmn = fminf(tmn, __shfl_xor(tmn, off));
        tmx = fmaxf(tmx, __shfl_xor(tmx, off));
    }
    if (lane == 0) {
        // blur values strictly positive -> float order == int order
        atomicMin(&mm[2 * img], __float_as_int(tmn));
        atomicMax(&mm[2 * img + 1], __float_as_int(tmx));
    }
}

// Normalize + emit both masks as INT32 0/1 (bool output dtype -> int32).
// blurNe holds blur f32 bit patterns on entry (second half of d_out used as
// scratch); each thread overwrites exactly the elements it read.
__global__ __launch_bounds__(256) void mask_kernel(
        const int* __restrict__ mm, int* __restrict__ edge,
        int* __restrict__ blurNe, long long n4) {
#pragma clang fp contract(off)
    const long long stride = (long long)gridDim.x * blockDim.x;
    for (long long i = (long long)blockIdx.x * blockDim.x + threadIdx.x;
         i < n4; i += stride) {
        int img = (int)(i >> 16);  // 262144/4 = 65536 vec4 per image
        float mn = __int_as_float(mm[2 * img]);
        float mx = __int_as_float(mm[2 * img + 1]);
        float d = mx - mn;
        int4 vi = reinterpret_cast<const int4*>(blurNe)[i];
        float4 v = make_float4(__int_as_float(vi.x), __int_as_float(vi.y),
                               __int_as_float(vi.z), __int_as_float(vi.w));
        // true division to match reference normalization exactly
        float n0 = (v.x - mn) / d;
        float n1 = (v.y - mn) / d;
        float n2 = (v.z - mn) / d;
        float n3 = (v.w - mn) / d;
        int4 e, ne;
        e.x = (n0 < 0.1f) ? 1 : 0;  ne.x = 1 - e.x;
        e.y = (n1 < 0.1f) ? 1 : 0;  ne.y = 1 - e.y;
        e.z = (n2 < 0.1f) ? 1 : 0;  ne.z = 1 - e.z;
        e.w = (n3 < 0.1f) ? 1 : 0;  ne.w = 1 - e.w;
        reinterpret_cast<int4*>(edge)[i] = e;
        reinterpret_cast<int4*>(blurNe)[i] = ne;
    }
}

extern "C" void kernel_launch(void* const* d_in, const int* in_sizes, int n_in,
                              void* d_out, int out_size, void* d_ws, size_t ws_size,
                              hipStream_t stream) {
    const float* x = (const float*)d_in[0];
    int* out = (int*)d_out;
    const long long N = (long long)in_sizes[0];        // 33554432
    const int nimg = (int)(N / IMG_PIX);               // 128
    float* blur = (float*)(out + N);                   // scratch in 2nd output half
    int* mm = (int*)d_ws;                              // 2 ints per image

    // f32 Gaussian weights, mimicking the jnp float32 ops
    Weights wt;
    {
        float tmp[13];
        float s = 0.0f;
        for (int i = 0; i < 7; ++i) {
            float t = (float)i - 3.0f;
            float u = t / 10.0f;
            tmp[i] = expf(-0.5f * (u * u));
            s += tmp[i];
        }
        for (int i = 0; i < 7; ++i) wt.kx[i] = tmp[i] / s;
        s = 0.0f;
        for (int i = 0; i < 13; ++i) {
            float t = (float)i - 6.0f;
            float u = t / 10.0f;
            tmp[i] = expf(-0.5f * (u * u));
            s += tmp[i];
        }
        for (int i = 0; i < 13; ++i) wt.ky[i] = tmp[i] / s;
    }

    init_minmax_kernel<<<1, 256, 0, stream>>>(mm, nimg);
    blur_kernel<<<dim3(5, 2, nimg), 256, 0, stream>>>(x, blur, mm, wt);
    mask_kernel<<<2048, 256, 0, stream>>>(mm, out, (int*)blur, N / 4);
}

// Round 10
// 224.755 us; speedup vs baseline: 2.0197x; 2.0197x over previous
//
#include <hip/hip_runtime.h>
#include <cmath>

// Problem geometry (fixed by the reference): 128 images of 512x512 f32.
static constexpr int IMH = 512;
static constexpr int IMW = 512;
static constexpr int IMG_PIX = IMH * IMW;

struct Weights {
    float kx[7];
    float ky[13];
};

__global__ void init_minmax_kernel(int* __restrict__ mm, int nimg) {
    int i = blockIdx.x * blockDim.x + threadIdx.x;
    if (i < nimg) {
        mm[2 * i]     = 0x7f7fffff;  // +FLT_MAX bits (min accumulator)
        mm[2 * i + 1] = 0;           // 0.0f bits (max accumulator; blur > 0)
    }
}

// DPP whole-wave shift, VALU-speed cross-lane. 0x130 = wave_shl:1
// (out[i] = in[i-1], out[0] = 0), 0x138 = wave_shr:1 (out[i] = in[i+1],
// out[63] = 0). gfx9-family control codes; bound_ctrl=1 zeroes edge lanes.
template <int CTRL>
__device__ __forceinline__ float gm_dpp(float v) {
    return __int_as_float(__builtin_amdgcn_update_dpp(
        0, __float_as_int(v), CTRL, 0xF, 0xF, true));
}

// Column-sweep fused kernel: zero LDS usage (not even bpermute), zero
// barriers. Wave = 64 lanes <-> 64 columns (56 outputs + halo). 4 waves per
// block sweep 4 independent ~134/140-row chunks. Per row: grad via register
// history + 2 DPP shifts, blurX via 6 DPP shifts, blurY via a 13-register
// ring with static indexing. Reflect padding is folded into the LOAD column
// of halo lanes (x[reflect(c)]); the left/right swap this causes in the
// horizontal gradient vanishes under squaring, so all consumed values are
// bit-identical to the reference. FP contraction off (mul-then-add order).
__global__ __launch_bounds__(256) void blur_kernel(
        const float* __restrict__ in, float* __restrict__ blur,
        int* __restrict__ mm, Weights wt) {
#pragma clang fp contract(off)
    const int band = blockIdx.x;              // 0..9
    const int img  = blockIdx.y;              // 0..127
    const int k    = threadIdx.x >> 6;        // row chunk 0..3
    const int lane = threadIdx.x & 63;
    const int cb   = band * 56 - 4;           // wave covers cols cb..cb+63
    const int c    = cb + lane;
    // Load column: reflect out-of-image halo columns (grad commutes with
    // reflection up to a sign that squaring erases).
    int lc = c < 0 ? -c : (c > IMW - 1 ? 2 * (IMW - 1) - c : c);
    const bool cvalid = (lane >= 4) && (lane <= 59) && (c <= IMW - 1);
    const bool has_l  = (lc >= 1);            // zero-pad guard at image edge
    const bool has_r  = (lc <= IMW - 2);

    const float* __restrict__ ip = in + (size_t)img * IMG_PIX;
    float* __restrict__ bp = blur + (size_t)img * IMG_PIX;

    const int gr0    = (k == 0) ? 0 : 128 * k - 6;       // first bx row
    const int gr_end = (k == 3) ? IMH - 1 : 128 * k + 133;
    const int tail_n = gr_end - gr0 - 129;               // 4 or 10

    // x register pipeline: rows gr-1, gr, gr+1 (+1 prefetch), moving pointers
    const float* xp = ip + (size_t)gr0 * IMW + lc;
    float x_prev = (k == 0) ? 0.0f : xp[-IMW];
    float x_cur  = xp[0];
    float x_next = xp[IMW];
    const float* xp_pref = xp + 2 * (size_t)IMW;
    float* op = bp + (size_t)(gr0 + 6) * IMW + c;        // first regular orow

    float w[13];                                          // bx ring, static idx
    float tmn = 3.402823466e38f;
    float tmx = 0.0f;

#define GM_ROW(S, DO_OUT, DN, PREF)                                            \
    {                                                                          \
        float x_pref = (PREF);                                                 \
        float xl_ = gm_dpp<0x130>(x_cur);    /* x[col-1] */                    \
        float xr_ = gm_dpp<0x138>(x_cur);    /* x[col+1] */                    \
        float lf_ = has_l ? xl_ : 0.0f;                                        \
        float rt_ = has_r ? xr_ : 0.0f;                                        \
        float gv_ = (DN) - x_prev;                                             \
        float gh_ = rt_ - lf_;                                                 \
        float sg_ = gv_ * gv_ + gh_ * gh_;   /* contract(off): mul,mul,add */  \
        sg_ = sg_ + 1e-6f;                                                     \
        float g_ = sqrtf(sg_);                                                 \
        float gm1_ = gm_dpp<0x130>(g_);                                        \
        float gm2_ = gm_dpp<0x130>(gm1_);                                      \
        float gm3_ = gm_dpp<0x130>(gm2_);                                      \
        float gp1_ = gm_dpp<0x138>(g_);                                        \
        float gp2_ = gm_dpp<0x138>(gp1_);                                      \
        float gp3_ = gm_dpp<0x138>(gp2_);                                      \
        float ax_ = 0.0f;                                                      \
        ax_ += wt.kx[0] * gm3_;                                                \
        ax_ += wt.kx[1] * gm2_;                                                \
        ax_ += wt.kx[2] * gm1_;                                                \
        ax_ += wt.kx[3] * g_;                                                  \
        ax_ += wt.kx[4] * gp1_;                                                \
        ax_ += wt.kx[5] * gp2_;                                                \
        ax_ += wt.kx[6] * gp3_;                                                \
        w[(S) % 13] = ax_;                                                     \
        if (DO_OUT) {                                                          \
            float ay_ = 0.0f;                                                  \
            ay_ += wt.ky[0]  * w[((S) + 1)  % 13];                             \
            ay_ += wt.ky[1]  * w[((S) + 2)  % 13];                             \
            ay_ += wt.ky[2]  * w[((S) + 3)  % 13];                             \
            ay_ += wt.ky[3]  * w[((S) + 4)  % 13];                             \
            ay_ += wt.ky[4]  * w[((S) + 5)  % 13];                             \
            ay_ += wt.ky[5]  * w[((S) + 6)  % 13];                             \
            ay_ += wt.ky[6]  * w[((S) + 7)  % 13];                             \
            ay_ += wt.ky[7]  * w[((S) + 8)  % 13];                             \
            ay_ += wt.ky[8]  * w[((S) + 9)  % 13];                             \
            ay_ += wt.ky[9]  * w[((S) + 10) % 13];                             \
            ay_ += wt.ky[10] * w[((S) + 11) % 13];                             \
            ay_ += wt.ky[11] * w[((S) + 12) % 13];                             \
            ay_ += wt.ky[12] * w[((S) + 13) % 13];                             \
            if (cvalid) {                                                      \
                *op = ay_;                                                     \
                tmn = fminf(tmn, ay_);                                         \
                tmx = fmaxf(tmx, ay_);                                         \
            }                                                                  \
            op += IMW;                                                         \
        }                                                                      \
        x_prev = x_cur; x_cur = x_next; x_next = x_pref;                       \
        xp_pref += IMW;                                                        \
    }

    // ---- peel: ring fill, rows gr0..gr0+12 (one output at s=12) ----
    GM_ROW(0,  false, x_next, xp_pref[0])
    GM_ROW(1,  false, x_next, xp_pref[0])
    GM_ROW(2,  false, x_next, xp_pref[0])
    GM_ROW(3,  false, x_next, xp_pref[0])
    GM_ROW(4,  false, x_next, xp_pref[0])
    GM_ROW(5,  false, x_next, xp_pref[0])
    GM_ROW(6,  false, x_next, xp_pref[0])
    GM_ROW(7,  false, x_next, xp_pref[0])
    GM_ROW(8,  false, x_next, xp_pref[0])
    GM_ROW(9,  false, x_next, xp_pref[0])
    GM_ROW(10, false, x_next, xp_pref[0])
    GM_ROW(11, false, x_next, xp_pref[0])
    GM_ROW(12, true,  x_next, xp_pref[0])

    // ---- top reflected outputs (k==0: rows 0..5 from ring rows 0..11) ----
    if (k == 0) {
        #pragma unroll
        for (int orow = 0; orow < 6; ++orow) {
            float ay = 0.0f;
            #pragma unroll
            for (int j = 0; j < 13; ++j) {
                int t = orow + j - 6;
                t = t < 0 ? -t : t;              // compile-time per (orow,j)
                ay += wt.ky[j] * w[t];           // slot == row for k==0
            }
            if (cvalid) {
                bp[(size_t)orow * IMW + c] = ay;
                tmn = fminf(tmn, ay);
                tmx = fmaxf(tmx, ay);
            }
        }
    }

    // ---- main loop: rows gr0+13 .. gr0+129, fully guard-free ----
    for (int giter = 1; giter <= 9; ++giter) {
        GM_ROW(0,  true, x_next, xp_pref[0])
        GM_ROW(1,  true, x_next, xp_pref[0])
        GM_ROW(2,  true, x_next, xp_pref[0])
        GM_ROW(3,  true, x_next, xp_pref[0])
        GM_ROW(4,  true, x_next, xp_pref[0])
        GM_ROW(5,  true, x_next, xp_pref[0])
        GM_ROW(6,  true, x_next, xp_pref[0])
        GM_ROW(7,  true, x_next, xp_pref[0])
        GM_ROW(8,  true, x_next, xp_pref[0])
        GM_ROW(9,  true, x_next, xp_pref[0])
        GM_ROW(10, true, x_next, xp_pref[0])
        GM_ROW(11, true, x_next, xp_pref[0])
        GM_ROW(12, true, x_next, xp_pref[0])
    }

    // ---- tail: rows gr0+130 .. gr_end (4 or 10 rows), guarded ----
    // slot (130+S)%13 == S; row 511 (k==3, S==3) takes dn=0; prefetch guarded.
#define GM_TAILROW(S)                                                          \
    if ((S) < tail_n) {                                                        \
        GM_ROW(S, true,                                                        \
               ((gr0 + 130 + (S)) == IMH - 1) ? 0.0f : x_next,                 \
               ((gr0 + 132 + (S)) <= IMH - 1) ? xp_pref[0] : 0.0f)             \
    }
    GM_TAILROW(0)
    GM_TAILROW(1)
    GM_TAILROW(2)
    GM_TAILROW(3)
    GM_TAILROW(4)
    GM_TAILROW(5)
    GM_TAILROW(6)
    GM_TAILROW(7)
    GM_TAILROW(8)
    GM_TAILROW(9)
#undef GM_TAILROW
#undef GM_ROW

    // ---- bottom reflected outputs (k==3: rows 506..511) ----
    // Row t (500..511) sits at slot (t-378)%13 after the sweep.
    if (k == 3) {
        #pragma unroll
        for (int oo = 0; oo < 6; ++oo) {
            int orow = 506 + oo;
            float ay = 0.0f;
            #pragma unroll
            for (int j = 0; j < 13; ++j) {
                int t = orow + j - 6;
                t = t > IMH - 1 ? 2 * (IMH - 1) - t : t;  // compile-time
                ay += wt.ky[j] * w[(t - 378) % 13];
            }
            if (cvalid) {
                bp[(size_t)orow * IMW + c] = ay;
                tmn = fminf(tmn, ay);
                tmx = fmaxf(tmx, ay);
            }
        }
    }

    // ---- per-wave reduce + per-image atomics ----
    #pragma unroll
    for (int off = 32; off > 0; off >>= 1) {
        tmn = fminf(tmn, __shfl_xor(tmn, off));
        tmx = fmaxf(tmx, __shfl_xor(tmx, off));
    }
    if (lane == 0) {
        // blur values strictly positive -> float order == int order
        atomicMin(&mm[2 * img], __float_as_int(tmn));
        atomicMax(&mm[2 * img + 1], __float_as_int(tmx));
    }
}

// Normalize + emit both masks as INT32 0/1 (bool output dtype -> int32).
// blurNe holds blur f32 bit patterns on entry (second half of d_out used as
// scratch); each thread overwrites exactly the elements it read.
__global__ __launch_bounds__(256) void mask_kernel(
        const int* __restrict__ mm, int* __restrict__ edge,
        int* __restrict__ blurNe, long long n4) {
#pragma clang fp contract(off)
    const long long stride = (long long)gridDim.x * blockDim.x;
    for (long long i = (long long)blockIdx.x * blockDim.x + threadIdx.x;
         i < n4; i += stride) {
        int img = (int)(i >> 16);  // 262144/4 = 65536 vec4 per image
        float mn = __int_as_float(mm[2 * img]);
        float mx = __int_as_float(mm[2 * img + 1]);
        float d = mx - mn;
        int4 vi = reinterpret_cast<const int4*>(blurNe)[i];
        float4 v = make_float4(__int_as_float(vi.x), __int_as_float(vi.y),
                               __int_as_float(vi.z), __int_as_float(vi.w));
        // true division to match reference normalization exactly
        float n0 = (v.x - mn) / d;
        float n1 = (v.y - mn) / d;
        float n2 = (v.z - mn) / d;
        float n3 = (v.w - mn) / d;
        int4 e, ne;
        e.x = (n0 < 0.1f) ? 1 : 0;  ne.x = 1 - e.x;
        e.y = (n1 < 0.1f) ? 1 : 0;  ne.y = 1 - e.y;
        e.z = (n2 < 0.1f) ? 1 : 0;  ne.z = 1 - e.z;
        e.w = (n3 < 0.1f) ? 1 : 0;  ne.w = 1 - e.w;
        reinterpret_cast<int4*>(edge)[i] = e;
        reinterpret_cast<int4*>(blurNe)[i] = ne;
    }
}

extern "C" void kernel_launch(void* const* d_in, const int* in_sizes, int n_in,
                              void* d_out, int out_size, void* d_ws, size_t ws_size,
                              hipStream_t stream) {
    const float* x = (const float*)d_in[0];
    int* out = (int*)d_out;
    const long long N = (long long)in_sizes[0];        // 33554432
    const int nimg = (int)(N / IMG_PIX);               // 128
    float* blur = (float*)(out + N);                   // scratch in 2nd output half
    int* mm = (int*)d_ws;                              // 2 ints per image

    // f32 Gaussian weights, mimicking the jnp float32 ops
    Weights wt;
    {
        float tmp[13];
        float s = 0.0f;
        for (int i = 0; i < 7; ++i) {
            float t = (float)i - 3.0f;
            float u = t / 10.0f;
            tmp[i] = expf(-0.5f * (u * u));
            s += tmp[i];
        }
        for (int i = 0; i < 7; ++i) wt.kx[i] = tmp[i] / s;
        s = 0.0f;
        for (int i = 0; i < 13; ++i) {
            float t = (float)i - 6.0f;
            float u = t / 10.0f;
            tmp[i] = expf(-0.5f * (u * u));
            s += tmp[i];
        }
        for (int i = 0; i < 13; ++i) wt.ky[i] = tmp[i] / s;
    }

    init_minmax_kernel<<<1, 256, 0, stream>>>(mm, nimg);
    blur_kernel<<<dim3(10, nimg), 256, 0, stream>>>(x, blur, mm, wt);
    mask_kernel<<<2048, 256, 0, stream>>>(mm, out, (int*)blur, N / 4);
}